// Round 9
// baseline (201.298 us; speedup 1.0000x reference)
//
#include <hip/hip_runtime.h>
#include <hip/hip_bf16.h>

// ---------------------------------------------------------------------------
// R9: single-pass attention stats, fragment-native layouts.
//   gap_att[c] = sum_j W[j,c]/Z[j],  W[j,c] = sum_i p_ij v[i,c],
//   Z[j] = sum_i p_ij,  p_ij = exp2(e2_ij),  v = pr+pd  (stored TRANSPOSED
//   as pvT[c][i] so the W^T-GEMM A-frag is one 8B vector load).
// p from the e-MFMA D-layout is the W-GEMM B-frag in-register (validated R8).
// R8 lesson: 1024thr+lb(,4) => 64-VGPR cap => 16 scalar loads serialized
// (~3560 cy/iter, 95.9us). R9: 512thr, 4 vec loads/iter, 3KB LDS.
// Pipeline: k_prep -> k_front(+pvT) -> k_col2 -> k_gate.
// ---------------------------------------------------------------------------

typedef __bf16 bf16;
typedef __bf16 bf16x4 __attribute__((ext_vector_type(4)));
typedef __bf16 bf16x8 __attribute__((ext_vector_type(8)));
typedef float  f32x4  __attribute__((ext_vector_type(4)));
typedef short  s4     __attribute__((ext_vector_type(4)));

#define MFMA_BF16(a, b, c) __builtin_amdgcn_mfma_f32_16x16x32_bf16((a), (b), (c), 0, 0, 0)

#if defined(__has_builtin)
# if __has_builtin(__builtin_amdgcn_mfma_f32_16x16x16bf16_1k)
#  define MFMA16_BUILTIN(a, b, c) __builtin_amdgcn_mfma_f32_16x16x16bf16_1k((a), (b), (c), 0, 0, 0)
# elif __has_builtin(__builtin_amdgcn_mfma_f32_16x16x16_bf16)
#  define MFMA16_BUILTIN(a, b, c) __builtin_amdgcn_mfma_f32_16x16x16_bf16((a), (b), (c), 0, 0, 0)
# endif
#endif

__device__ __forceinline__ f32x4 MFMA16(s4 a, s4 b, f32x4 c) {
#ifdef MFMA16_BUILTIN
    return MFMA16_BUILTIN(a, b, c);
#else
    asm("v_mfma_f32_16x16x16_bf16 %0, %1, %2, %0" : "+v"(c) : "v"(a), "v"(b));
    return c;
#endif
}

#if defined(__has_builtin)
# if __has_builtin(__builtin_amdgcn_exp2f)
#  define EXP2(x) __builtin_amdgcn_exp2f(x)
# else
#  define EXP2(x) exp2f(x)
# endif
#else
# define EXP2(x) exp2f(x)
#endif

#define K_E 0.18033688f      // 0.125 * log2(e)

__device__ __forceinline__ int swz128(int row, int colByte) {
    return row * 128 + (colByte ^ ((row & 7) << 4));
}

// ---------------------------------------------------------------------------
// K0: pack weights into fragment-ordered bf16.
// ---------------------------------------------------------------------------
__global__ __launch_bounds__(256) void k_prep(
    const float* __restrict__ conv_w, const float* __restrict__ rgb_w,
    const float* __restrict__ dep_w,
    bf16* __restrict__ wC, bf16* __restrict__ wR, bf16* __restrict__ wD)
{
    const int gid = blockIdx.x * 256 + threadIdx.x;
    bf16x8 v;
    if (gid < 2048) {
        const int t = gid >> 9, kk = (gid >> 6) & 7, lane = gid & 63;
        const float* src = conv_w + (size_t)(t * 16 + (lane & 15)) * 256
                                  + kk * 32 + (lane >> 4) * 8;
        #pragma unroll
        for (int j = 0; j < 8; ++j) v[j] = (bf16)src[j];
        *(bf16x8*)(wC + (size_t)gid * 8) = v;
    } else if (gid < 2560) {
        const int g = gid - 2048;
        const int t = g >> 7, kk = (g >> 6) & 1, lane = g & 63;
        const float* src = rgb_w + (size_t)(t * 16 + (lane & 15)) * 64
                                 + kk * 32 + (lane >> 4) * 8;
        #pragma unroll
        for (int j = 0; j < 8; ++j) v[j] = (bf16)src[j];
        *(bf16x8*)(wR + (size_t)g * 8) = v;
    } else {
        const int g = gid - 2560;
        const int t = g >> 7, kk = (g >> 6) & 1, lane = g & 63;
        const float* src = dep_w + (size_t)(t * 16 + (lane & 15)) * 64
                                 + kk * 32 + (lane >> 4) * 8;
        #pragma unroll
        for (int j = 0; j < 8; ++j) v[j] = (bf16)src[j];
        *(bf16x8*)(wD + (size_t)g * 8) = v;
    }
}

// ---------------------------------------------------------------------------
// K1: conv+BN+ReLU -> proj: pr_e (exp2-scaled), pd, pvT[c][i]; rgbd partials.
// ---------------------------------------------------------------------------
__global__ __launch_bounds__(512, 4) void k_front(
    const float* __restrict__ rgb, const float* __restrict__ dep,
    const bf16* __restrict__ wC, const bf16* __restrict__ wR,
    const bf16* __restrict__ wD,
    const float* __restrict__ bn1_g, const float* __restrict__ bn1_b,
    const float* __restrict__ bn1_m, const float* __restrict__ bn1_v,
    bf16* __restrict__ pr_e, bf16* __restrict__ pd, bf16* __restrict__ pvT,
    float* __restrict__ rgbdPart)
{
    const int bid = blockIdx.x;
    const int xcd = bid & 7;
    const int b    = xcd >> 1;
    const int tile = ((bid >> 3) << 1) | (xcd & 1);
    const int p0   = tile * 32;
    const int tid = threadIdx.x;
    const int w   = tid >> 6;
    const int lane = tid & 63;
    const int l15 = lane & 15;
    const int lg  = lane >> 4;
    const int ot4 = w & 3;
    const int ot  = ot4 * 16;
    const int ph  = w >> 2;

    __shared__ float s1[64], b1[64];
    __shared__ __align__(16) unsigned char ldsD[32 * 128];
    __shared__ __align__(16) unsigned char ldsR[32 * 128];
    __shared__ float red[8][64];

    if (tid < 64) {
        float sc = bn1_g[tid] * rsqrtf(bn1_v[tid] + 1e-5f);
        s1[tid] = sc;
        b1[tid] = bn1_b[tid] - bn1_m[tid] * sc;
    }
    __syncthreads();

    bf16x8 aW[8];
    #pragma unroll
    for (int kk = 0; kk < 8; ++kk)
        aW[kk] = *(const bf16x8*)(wC + ((size_t)(ot4 * 8 + kk) * 64 + lane) * 8);

    const float* depb = dep + (size_t)b * 256 * 4096;
    const int p = p0 + ph * 16 + l15;
    f32x4 acc = {0.f, 0.f, 0.f, 0.f};
    #pragma unroll
    for (int kk = 0; kk < 8; ++kk) {
        bf16x8 bF;
        const int c0 = kk * 32 + lg * 8;
        #pragma unroll
        for (int j = 0; j < 8; ++j) bF[j] = (bf16)depb[(size_t)(c0 + j) * 4096 + p];
        acc = MFMA_BF16(aW[kk], bF, acc);
    }
    {
        const int pl = ph * 16 + l15;
        const int o0 = ot + lg * 4;
        bf16x4 v4;
        #pragma unroll
        for (int r = 0; r < 4; ++r) {
            float x = acc[r] * s1[o0 + r] + b1[o0 + r];
            v4[r] = (bf16)(x > 0.f ? x : 0.f);
        }
        *(bf16x4*)(ldsD + swz128(pl, o0 * 2)) = v4;
    }
    const float* rgbb = rgb + (size_t)b * 64 * 4096;
    #pragma unroll
    for (int rep = 0; rep < 4; ++rep) {
        const int idx = rep * 512 + tid;
        const int c = idx >> 5, pp = idx & 31;
        *(bf16*)(ldsR + swz128(pp, c * 2)) = (bf16)rgbb[(size_t)c * 4096 + p0 + pp];
    }
    __syncthreads();

    bf16x8 aR[2], aD[2];
    #pragma unroll
    for (int kk = 0; kk < 2; ++kk) {
        aR[kk] = *(const bf16x8*)(wR + ((size_t)(ot4 * 2 + kk) * 64 + lane) * 8);
        aD[kk] = *(const bf16x8*)(wD + ((size_t)(ot4 * 2 + kk) * 64 + lane) * 8);
    }
    {
        f32x4 accR = {0.f, 0.f, 0.f, 0.f}, accD = {0.f, 0.f, 0.f, 0.f};
        const int pl = ph * 16 + l15;
        #pragma unroll
        for (int kk = 0; kk < 2; ++kk) {
            const int cb = (kk * 32 + lg * 8) * 2;
            bf16x8 bR = *(const bf16x8*)(ldsR + swz128(pl, cb));
            bf16x8 bD = *(const bf16x8*)(ldsD + swz128(pl, cb));
            accR = MFMA_BF16(aR[kk], bR, accR);
            accD = MFMA_BF16(aD[kk], bD, accD);
        }
        bf16x4 vR, vD;
        #pragma unroll
        for (int r = 0; r < 4; ++r) {
            vR[r] = (bf16)(accR[r] * K_E);
            vD[r] = (bf16)accD[r];
        }
        const size_t ob = ((size_t)b * 4096 + p0 + pl) * 64 + ot + lg * 4;
        *(bf16x4*)(pr_e + ob) = vR;
        *(bf16x4*)(pd + ob) = vD;
        // pvT[c][i]: 4 scalar stores (scatter ok: fire-and-forget)
        bf16* tb = pvT + (size_t)b * 64 * 4096 + (size_t)(ot + lg * 4) * 4096
                 + p0 + pl;
        #pragma unroll
        for (int r = 0; r < 4; ++r)
            tb[(size_t)r * 4096] = (bf16)(accR[r] + accD[r]);
    }
    {
        const int c = tid & 63, g8 = tid >> 6;
        float sum = 0.f;
        #pragma unroll
        for (int q = 0; q < 4; ++q) {
            const int pp = g8 * 4 + q;
            sum += (float)*(const bf16*)(ldsR + swz128(pp, c * 2))
                 + (float)*(const bf16*)(ldsD + swz128(pp, c * 2));
        }
        red[g8][c] = sum;
    }
    __syncthreads();
    if (tid < 64) {
        float s = 0.f;
        #pragma unroll
        for (int g = 0; g < 8; ++g) s += red[g][tid];
        rgbdPart[((size_t)b * 128 + tile) * 64 + tid] = s;
    }
}

// ---------------------------------------------------------------------------
// K2 v2: single-pass column stats. 1024 blocks (4b x 256 j-tiles of 16,
// XCD-affine) x 512 thr (8 waves = 8-way i-split, 32 iters each).
// Per iter/wave: e=pr_e x pd (2 MFMA K=32), p=exp2(e) (stays in regs as the
// W-GEMM B-frag), 4x { 8B pvT vec load -> MFMA16 accWT[cb] }.
// Epilogue: Z cross-wave reduce (LDS), g = sum_j W^T[c,j]*zinv_j via shfl.
// LDS ~3KB, VGPR budget 128 (lb 512,4) -> no load serialization (R8 lesson).
// ---------------------------------------------------------------------------
__global__ __launch_bounds__(512, 4) void k_col2(
    const bf16* __restrict__ pr_e, const bf16* __restrict__ pd,
    const bf16* __restrict__ pvT, float* __restrict__ gapPart)
{
    const int bid = blockIdx.x;
    const int xcd = bid & 7, b = xcd >> 1;
    const int jt = ((bid >> 3) << 1) | (xcd & 1);   // 0..255
    const int j0 = jt * 16;
    const int tid = threadIdx.x;
    const int ih = tid >> 6, lane = tid & 63;
    const int l15 = lane & 15, lg = lane >> 4;

    __shared__ float z_lds[8][16];
    __shared__ float zfull[16];
    __shared__ float g_lds[8][64];

    const bf16* prb  = pr_e + (size_t)b * 4096 * 64;
    const bf16* pdb  = pd   + (size_t)b * 4096 * 64;
    const bf16* pvtb = pvT  + (size_t)b * 64 * 4096;
    const int cOff = lg * 8;

    // resident e-GEMM B operand: pd rows j0..j0+15
    bf16x8 b0, b1;
    {
        const bf16* q = pdb + (size_t)(j0 + l15) * 64 + cOff;
        b0 = *(const bf16x8*)q;
        b1 = *(const bf16x8*)(q + 32);
    }

    f32x4 accWT[4] = {{0,0,0,0},{0,0,0,0},{0,0,0,0},{0,0,0,0}};
    float z = 0.f;
    const bf16* pa  = prb  + ((size_t)ih * 16 + l15) * 64 + cOff;
    const bf16* pv0 = pvtb + (size_t)l15 * 4096 + ih * 16 + lg * 4;

    for (int q = 0; q < 32; ++q) {
        bf16x8 a0 = *(const bf16x8*)pa;
        bf16x8 a1 = *(const bf16x8*)(pa + 32);
        pa += 128 * 64;                       // 128 rows ahead (8 waves x 16)
        // vT A-frags: independent of e-chain, issue early
        bf16x4 vt0 = *(const bf16x4*)(pv0);
        bf16x4 vt1 = *(const bf16x4*)(pv0 + 16 * 4096);
        bf16x4 vt2 = *(const bf16x4*)(pv0 + 32 * 4096);
        bf16x4 vt3 = *(const bf16x4*)(pv0 + 48 * 4096);
        pv0 += 128;

        f32x4 e = {0.f, 0.f, 0.f, 0.f};
        e = MFMA_BF16(a0, b0, e);
        e = MFMA_BF16(a1, b1, e);
        bf16x4 ph;
        #pragma unroll
        for (int r = 0; r < 4; ++r) {
            float pf = EXP2(e[r]);
            z += pf;
            ph[r] = (bf16)pf;
        }
        const s4 pB = __builtin_bit_cast(s4, ph);
        accWT[0] = MFMA16(__builtin_bit_cast(s4, vt0), pB, accWT[0]);
        accWT[1] = MFMA16(__builtin_bit_cast(s4, vt1), pB, accWT[1]);
        accWT[2] = MFMA16(__builtin_bit_cast(s4, vt2), pB, accWT[2]);
        accWT[3] = MFMA16(__builtin_bit_cast(s4, vt3), pB, accWT[3]);
    }

    // Z: full column sums (j = j0 + l15)
    z += __shfl_xor(z, 16);
    z += __shfl_xor(z, 32);
    if (lane < 16) z_lds[ih][lane] = z;
    __syncthreads();
    if (tid < 16) {
        float s = 0.f;
        #pragma unroll
        for (int k = 0; k < 8; ++k) s += z_lds[k][tid];
        zfull[tid] = s;
    }
    __syncthreads();
    const float zj = zfull[l15];
    float zinv = __builtin_amdgcn_rcpf(zj);
    zinv = zinv * (2.0f - zj * zinv);

    // g[c] partial = sum over this lane's j (=l15) then over l15 group
    #pragma unroll
    for (int cb = 0; cb < 4; ++cb) {
        #pragma unroll
        for (int r = 0; r < 4; ++r) {
            float v = accWT[cb][r] * zinv;
            v += __shfl_xor(v, 1);
            v += __shfl_xor(v, 2);
            v += __shfl_xor(v, 4);
            v += __shfl_xor(v, 8);
            if (l15 == 0) g_lds[ih][cb * 16 + lg * 4 + r] = v;
        }
    }
    __syncthreads();
    if (tid < 64) {
        float s = 0.f;
        #pragma unroll
        for (int k = 0; k < 8; ++k) s += g_lds[k][tid];
        gapPart[((size_t)b * 256 + jt) * 64 + tid] = s;
    }
}

// ---------------------------------------------------------------------------
// K3: gap assembly -> mlp1+BN+ReLU -> mlp2+BN -> sigmoid (f32 out).
// ---------------------------------------------------------------------------
__global__ __launch_bounds__(256) void k_gate(
    const float* __restrict__ gapPart, const float* __restrict__ rgbdPart,
    const float* __restrict__ mlp1_w,
    const float* __restrict__ bn2_g, const float* __restrict__ bn2_b,
    const float* __restrict__ bn2_m, const float* __restrict__ bn2_v,
    const float* __restrict__ mlp2_w,
    const float* __restrict__ bn3_g, const float* __restrict__ bn3_b,
    const float* __restrict__ bn3_m, const float* __restrict__ bn3_v,
    float* __restrict__ out)
{
    const int b = blockIdx.x, tid = threadIdx.x;
    const int c = tid & 63, g = tid >> 6;
    __shared__ float red[4][64];
    __shared__ float gv[64], h[24];

    float acc = 0.f;
    const float* rp = rgbdPart + ((size_t)b * 128 + g * 32) * 64 + c;
    #pragma unroll 4
    for (int t = 0; t < 32; ++t) acc += rp[t * 64];
    const float* gp = gapPart + ((size_t)b * 256 + g * 64) * 64 + c;
    #pragma unroll 4
    for (int t = 0; t < 64; ++t) acc += gp[t * 64];
    red[g][c] = acc;
    __syncthreads();
    if (tid < 64)
        gv[tid] = ((red[0][tid] + red[1][tid]) + (red[2][tid] + red[3][tid]))
                  * (1.f / 4096.f);
    __syncthreads();
    if (tid < 24) {
        float a = 0.f;
        #pragma unroll
        for (int cc = 0; cc < 64; ++cc) a += mlp1_w[tid * 64 + cc] * gv[cc];
        float sc = bn2_g[tid] * rsqrtf(bn2_v[tid] + 1e-5f);
        a = a * sc + bn2_b[tid] - bn2_m[tid] * sc;
        h[tid] = a > 0.f ? a : 0.f;
    }
    __syncthreads();
    if (tid < 64) {
        float u = 0.f;
        #pragma unroll
        for (int o = 0; o < 24; ++o) u += mlp2_w[tid * 24 + o] * h[o];
        float sc = bn3_g[tid] * rsqrtf(bn3_v[tid] + 1e-5f);
        u = u * sc + bn3_b[tid] - bn3_m[tid] * sc;
        out[b * 64 + tid] = 1.f / (1.f + __expf(-u));
    }
}

// ---------------------------------------------------------------------------
extern "C" void kernel_launch(void* const* d_in, const int* in_sizes, int n_in,
                              void* d_out, int out_size, void* d_ws, size_t ws_size,
                              hipStream_t stream)
{
    const float* rgb    = (const float*)d_in[0];
    const float* dep    = (const float*)d_in[1];
    const float* conv_w = (const float*)d_in[2];
    const float* bn1_g  = (const float*)d_in[3];
    const float* bn1_b  = (const float*)d_in[4];
    const float* bn1_m  = (const float*)d_in[5];
    const float* bn1_v  = (const float*)d_in[6];
    const float* rgb_w  = (const float*)d_in[7];
    const float* dep_w  = (const float*)d_in[8];
    const float* mlp1_w = (const float*)d_in[9];
    const float* bn2_g  = (const float*)d_in[10];
    const float* bn2_b  = (const float*)d_in[11];
    const float* bn2_m  = (const float*)d_in[12];
    const float* bn2_v  = (const float*)d_in[13];
    const float* mlp2_w = (const float*)d_in[14];
    const float* bn3_g  = (const float*)d_in[15];
    const float* bn3_b  = (const float*)d_in[16];
    const float* bn3_m  = (const float*)d_in[17];
    const float* bn3_v  = (const float*)d_in[18];

    char* ws = (char*)d_ws;
    bf16*  pr_e     = (bf16*)(ws);                                  // 2 MB
    bf16*  pdBuf    = (bf16*)(ws + (2u << 20));                     // 2 MB
    bf16*  pvT      = (bf16*)(ws + (4u << 20));                     // 2 MB
    float* rgbdPart = (float*)(ws + (6u << 20));                    // 128 KB
    float* gapPart  = (float*)(ws + (6u << 20) + (128u << 10));     // 256 KB
    bf16*  wC       = (bf16*)(ws + (6u << 20) + (384u << 10));      // 32 KB
    bf16*  wR       = (bf16*)(ws + (6u << 20) + (416u << 10));      // 8 KB
    bf16*  wD       = (bf16*)(ws + (6u << 20) + (424u << 10));      // 8 KB

    k_prep<<<12, 256, 0, stream>>>(conv_w, rgb_w, dep_w, wC, wR, wD);
    k_front<<<512, 512, 0, stream>>>(rgb, dep, wC, wR, wD,
                                     bn1_g, bn1_b, bn1_m, bn1_v,
                                     pr_e, pdBuf, pvT, rgbdPart);
    k_col2<<<1024, 512, 0, stream>>>(pr_e, pdBuf, pvT, gapPart);
    k_gate<<<4, 256, 0, stream>>>(gapPart, rgbdPart, mlp1_w,
                                  bn2_g, bn2_b, bn2_m, bn2_v, mlp2_w,
                                  bn3_g, bn3_b, bn3_m, bn3_v, (float*)d_out);
}

// Round 10
// 65.871 us; speedup vs baseline: 3.0559x; 3.0559x over previous
//
#include <hip/hip_runtime.h>
#include <hip/hip_bf16.h>

// ---------------------------------------------------------------------------
// R10: single-pass attention stats with LDS-staged tiles (TA-bound fix).
//   gap_att[c] = sum_j W[j,c]/Z[j],  W[j,c] = sum_i p_ij v[i,c],
//   Z[j] = sum_i p_ij,  p_ij = exp2(e2_ij),  v = pr+pd.
// R3-R9 lesson: MFMA fragment loads straight from global are address-divergent
// (16 lines/instr) -> TA serializes at ~1 line/cyc/CU -> ~3 TB/s ceiling seen
// in every attention kernel. Fix = canonical GEMM staging: coalesced global
// (32B/lane) -> reg -> XOR-swizzled LDS -> fragment ds_reads.
// k_front writes pv TILED: pvt[b][i>>7][c][i&127] so pv tile = 16KB contiguous.
// ---------------------------------------------------------------------------

typedef __bf16 bf16;
typedef __bf16 bf16x4 __attribute__((ext_vector_type(4)));
typedef __bf16 bf16x8 __attribute__((ext_vector_type(8)));
typedef float  f32x4  __attribute__((ext_vector_type(4)));
typedef short  s4     __attribute__((ext_vector_type(4)));
typedef int    i32x4  __attribute__((ext_vector_type(4)));

#define MFMA_BF16(a, b, c) __builtin_amdgcn_mfma_f32_16x16x32_bf16((a), (b), (c), 0, 0, 0)

#if defined(__has_builtin)
# if __has_builtin(__builtin_amdgcn_mfma_f32_16x16x16bf16_1k)
#  define MFMA16_BUILTIN(a, b, c) __builtin_amdgcn_mfma_f32_16x16x16bf16_1k((a), (b), (c), 0, 0, 0)
# elif __has_builtin(__builtin_amdgcn_mfma_f32_16x16x16_bf16)
#  define MFMA16_BUILTIN(a, b, c) __builtin_amdgcn_mfma_f32_16x16x16_bf16((a), (b), (c), 0, 0, 0)
# endif
#endif

__device__ __forceinline__ f32x4 MFMA16(s4 a, s4 b, f32x4 c) {
#ifdef MFMA16_BUILTIN
    return MFMA16_BUILTIN(a, b, c);
#else
    asm("v_mfma_f32_16x16x16_bf16 %0, %1, %2, %0" : "+v"(c) : "v"(a), "v"(b));
    return c;
#endif
}

#if defined(__has_builtin)
# if __has_builtin(__builtin_amdgcn_exp2f)
#  define EXP2(x) __builtin_amdgcn_exp2f(x)
# else
#  define EXP2(x) exp2f(x)
# endif
#else
# define EXP2(x) exp2f(x)
#endif

#define K_E 0.18033688f      // 0.125 * log2(e)

__device__ __forceinline__ int swz128(int row, int colByte) {
    return row * 128 + (colByte ^ ((row & 7) << 4));
}

// ---------------------------------------------------------------------------
// K0: pack weights into fragment-ordered bf16.
// ---------------------------------------------------------------------------
__global__ __launch_bounds__(256) void k_prep(
    const float* __restrict__ conv_w, const float* __restrict__ rgb_w,
    const float* __restrict__ dep_w,
    bf16* __restrict__ wC, bf16* __restrict__ wR, bf16* __restrict__ wD)
{
    const int gid = blockIdx.x * 256 + threadIdx.x;
    bf16x8 v;
    if (gid < 2048) {
        const int t = gid >> 9, kk = (gid >> 6) & 7, lane = gid & 63;
        const float* src = conv_w + (size_t)(t * 16 + (lane & 15)) * 256
                                  + kk * 32 + (lane >> 4) * 8;
        #pragma unroll
        for (int j = 0; j < 8; ++j) v[j] = (bf16)src[j];
        *(bf16x8*)(wC + (size_t)gid * 8) = v;
    } else if (gid < 2560) {
        const int g = gid - 2048;
        const int t = g >> 7, kk = (g >> 6) & 1, lane = g & 63;
        const float* src = rgb_w + (size_t)(t * 16 + (lane & 15)) * 64
                                 + kk * 32 + (lane >> 4) * 8;
        #pragma unroll
        for (int j = 0; j < 8; ++j) v[j] = (bf16)src[j];
        *(bf16x8*)(wR + (size_t)g * 8) = v;
    } else {
        const int g = gid - 2560;
        const int t = g >> 7, kk = (g >> 6) & 1, lane = g & 63;
        const float* src = dep_w + (size_t)(t * 16 + (lane & 15)) * 64
                                 + kk * 32 + (lane >> 4) * 8;
        #pragma unroll
        for (int j = 0; j < 8; ++j) v[j] = (bf16)src[j];
        *(bf16x8*)(wD + (size_t)g * 8) = v;
    }
}

// ---------------------------------------------------------------------------
// K1: conv+BN+ReLU -> proj: pr_e ([i][c], exp2-scaled), pd ([i][c]),
// pv TILED pvt[b][i>>7][c][i&127]; rgbd partials.
// ---------------------------------------------------------------------------
__global__ __launch_bounds__(512, 4) void k_front(
    const float* __restrict__ rgb, const float* __restrict__ dep,
    const bf16* __restrict__ wC, const bf16* __restrict__ wR,
    const bf16* __restrict__ wD,
    const float* __restrict__ bn1_g, const float* __restrict__ bn1_b,
    const float* __restrict__ bn1_m, const float* __restrict__ bn1_v,
    bf16* __restrict__ pr_e, bf16* __restrict__ pd, bf16* __restrict__ pvt,
    float* __restrict__ rgbdPart)
{
    const int bid = blockIdx.x;
    const int xcd = bid & 7;
    const int b    = xcd >> 1;
    const int tile = ((bid >> 3) << 1) | (xcd & 1);
    const int p0   = tile * 32;
    const int tid = threadIdx.x;
    const int w   = tid >> 6;
    const int lane = tid & 63;
    const int l15 = lane & 15;
    const int lg  = lane >> 4;
    const int ot4 = w & 3;
    const int ot  = ot4 * 16;
    const int ph  = w >> 2;

    __shared__ float s1[64], b1[64];
    __shared__ __align__(16) unsigned char ldsD[32 * 128];
    __shared__ __align__(16) unsigned char ldsR[32 * 128];
    __shared__ float red[8][64];

    if (tid < 64) {
        float sc = bn1_g[tid] * rsqrtf(bn1_v[tid] + 1e-5f);
        s1[tid] = sc;
        b1[tid] = bn1_b[tid] - bn1_m[tid] * sc;
    }
    __syncthreads();

    bf16x8 aW[8];
    #pragma unroll
    for (int kk = 0; kk < 8; ++kk)
        aW[kk] = *(const bf16x8*)(wC + ((size_t)(ot4 * 8 + kk) * 64 + lane) * 8);

    const float* depb = dep + (size_t)b * 256 * 4096;
    const int p = p0 + ph * 16 + l15;
    f32x4 acc = {0.f, 0.f, 0.f, 0.f};
    #pragma unroll
    for (int kk = 0; kk < 8; ++kk) {
        bf16x8 bF;
        const int c0 = kk * 32 + lg * 8;
        #pragma unroll
        for (int j = 0; j < 8; ++j) bF[j] = (bf16)depb[(size_t)(c0 + j) * 4096 + p];
        acc = MFMA_BF16(aW[kk], bF, acc);
    }
    {
        const int pl = ph * 16 + l15;
        const int o0 = ot + lg * 4;
        bf16x4 v4;
        #pragma unroll
        for (int r = 0; r < 4; ++r) {
            float x = acc[r] * s1[o0 + r] + b1[o0 + r];
            v4[r] = (bf16)(x > 0.f ? x : 0.f);
        }
        *(bf16x4*)(ldsD + swz128(pl, o0 * 2)) = v4;
    }
    const float* rgbb = rgb + (size_t)b * 64 * 4096;
    #pragma unroll
    for (int rep = 0; rep < 4; ++rep) {
        const int idx = rep * 512 + tid;
        const int c = idx >> 5, pp = idx & 31;
        *(bf16*)(ldsR + swz128(pp, c * 2)) = (bf16)rgbb[(size_t)c * 4096 + p0 + pp];
    }
    __syncthreads();

    bf16x8 aR[2], aD[2];
    #pragma unroll
    for (int kk = 0; kk < 2; ++kk) {
        aR[kk] = *(const bf16x8*)(wR + ((size_t)(ot4 * 2 + kk) * 64 + lane) * 8);
        aD[kk] = *(const bf16x8*)(wD + ((size_t)(ot4 * 2 + kk) * 64 + lane) * 8);
    }
    {
        f32x4 accR = {0.f, 0.f, 0.f, 0.f}, accD = {0.f, 0.f, 0.f, 0.f};
        const int pl = ph * 16 + l15;
        #pragma unroll
        for (int kk = 0; kk < 2; ++kk) {
            const int cb = (kk * 32 + lg * 8) * 2;
            bf16x8 bR = *(const bf16x8*)(ldsR + swz128(pl, cb));
            bf16x8 bD = *(const bf16x8*)(ldsD + swz128(pl, cb));
            accR = MFMA_BF16(aR[kk], bR, accR);
            accD = MFMA_BF16(aD[kk], bD, accD);
        }
        bf16x4 vR, vD;
        #pragma unroll
        for (int r = 0; r < 4; ++r) {
            vR[r] = (bf16)(accR[r] * K_E);
            vD[r] = (bf16)accD[r];
        }
        const int i = p0 + pl;
        const size_t ob = ((size_t)b * 4096 + i) * 64 + ot + lg * 4;
        *(bf16x4*)(pr_e + ob) = vR;
        *(bf16x4*)(pd + ob) = vD;
        // pv tiled: pvt[((b*32 + (i>>7))*64 + c)*128 + (i&127)]
        bf16* tb = pvt + (((size_t)b * 32 + (i >> 7)) * 64 + ot + lg * 4) * 128
                 + (i & 127);
        #pragma unroll
        for (int r = 0; r < 4; ++r)
            tb[(size_t)r * 128] = (bf16)(accR[r] + accD[r]);
    }
    {
        const int c = tid & 63, g8 = tid >> 6;
        float sum = 0.f;
        #pragma unroll
        for (int q = 0; q < 4; ++q) {
            const int pp = g8 * 4 + q;
            sum += (float)*(const bf16*)(ldsR + swz128(pp, c * 2))
                 + (float)*(const bf16*)(ldsD + swz128(pp, c * 2));
        }
        red[g8][c] = sum;
    }
    __syncthreads();
    if (tid < 64) {
        float s = 0.f;
        #pragma unroll
        for (int g = 0; g < 8; ++g) s += red[g][tid];
        rgbdPart[((size_t)b * 128 + tile) * 64 + tid] = s;
    }
}

// ---------------------------------------------------------------------------
// K2: LDS-staged single-pass column stats.
// 256 blocks (4b x 64 j-tiles of 64, XCD-affine) x 512 thr (8 waves:
// jt=w&3 owns 16 j, ih=w>>2 splits the 128-row i-tile).
// Per i-tile (x32): reg-stage pr(16KB)+pv(16KB) coalesced -> swizzled LDS
// (double-buffered, issue-early/write-late); per wave 4 subtiles of
// {2 ds_b128 -> 2 MFMA K=32 -> 4 exp2 -> 4 ds_b64 + 4 MFMA16}.
// Epilogue: Z cross-wave reduce, g = sum_j W^T[c,j]*zinv_j.
// ---------------------------------------------------------------------------
__global__ __launch_bounds__(512, 4) void k_colS(
    const bf16* __restrict__ pr_e, const bf16* __restrict__ pd,
    const bf16* __restrict__ pvt, float* __restrict__ gapPart)
{
    const int bid = blockIdx.x;
    const int xcd = bid & 7, b = xcd >> 1;
    const int jt64 = ((bid >> 3) << 1) | (xcd & 1);   // 0..63
    const int j0 = jt64 * 64;
    const int tid = threadIdx.x;
    const int w = tid >> 6, lane = tid & 63;
    const int l15 = lane & 15, lg = lane >> 4;
    const int jt = w & 3, ih = w >> 2;

    __shared__ __align__(16) bf16 prL[2][8192];   // [128 i][64 c], 128B rows, swz
    __shared__ __align__(16) bf16 pvL[2][8192];   // [64 c][128 i], 256B rows, swz
    __shared__ __align__(16) bf16 pdL[4096];      // [64 j][64 c], 128B rows, swz
    __shared__ float zred[8][16];
    __shared__ float gred[8][64];

    const bf16* prb  = pr_e + (size_t)b * 4096 * 64;
    const bf16* pdb  = pd   + (size_t)b * 4096 * 64;
    const bf16* pvtb = pvt  + (size_t)b * 32 * 8192;

    // ---- prologue: stage pd (8KB) + tile 0 (pr,pv 16KB each), coalesced ----
    {
        const char* gpr = (const char*)prb;
        const char* gpv = (const char*)pvtb;
        const char* gpd = (const char*)(pdb + (size_t)j0 * 64);
        const int o = tid * 32, o1 = o + 16, o2 = tid * 16;
        i32x4 t0 = *(const i32x4*)(gpr + o);
        i32x4 t1 = *(const i32x4*)(gpr + o1);
        i32x4 t2 = *(const i32x4*)(gpv + o);
        i32x4 t3 = *(const i32x4*)(gpv + o1);
        i32x4 t4 = *(const i32x4*)(gpd + o2);
        *(i32x4*)((char*)prL[0] + (o  ^ (((o  >> 7) & 7) << 4))) = t0;
        *(i32x4*)((char*)prL[0] + (o1 ^ (((o1 >> 7) & 7) << 4))) = t1;
        *(i32x4*)((char*)pvL[0] + (o  ^ (((o  >> 8) & 15) << 4))) = t2;
        *(i32x4*)((char*)pvL[0] + (o1 ^ (((o1 >> 8) & 15) << 4))) = t3;
        *(i32x4*)((char*)pdL    + (o2 ^ (((o2 >> 7) & 7) << 4))) = t4;
    }
    __syncthreads();

    // ---- resident b-frags: pd rows jt*16+l15 ----
    bf16x8 b0, b1;
    {
        const int rowJ = jt * 16 + l15;
        const char* pdc = (const char*)pdL;
        b0 = *(const bf16x8*)(pdc + rowJ * 128 + ((lg * 16)      ^ ((rowJ & 7) << 4)));
        b1 = *(const bf16x8*)(pdc + rowJ * 128 + ((64 + lg * 16) ^ ((rowJ & 7) << 4)));
    }

    f32x4 accWT[4] = {{0,0,0,0},{0,0,0,0},{0,0,0,0},{0,0,0,0}};
    float z = 0.f;
    int cur = 0;

    for (int t = 0; t < 32; ++t) {
        // issue next-tile global loads early (land under this tile's compute)
        i32x4 s0, s1, s2, s3;
        if (t < 31) {
            const char* gpr = (const char*)(prb  + (size_t)(t + 1) * 8192);
            const char* gpv = (const char*)(pvtb + (size_t)(t + 1) * 8192);
            const int o = tid * 32, o1 = o + 16;
            s0 = *(const i32x4*)(gpr + o);
            s1 = *(const i32x4*)(gpr + o1);
            s2 = *(const i32x4*)(gpv + o);
            s3 = *(const i32x4*)(gpv + o1);
        }
        // compute on buf[cur]
        const char* prc = (const char*)prL[cur];
        const char* pvc = (const char*)pvL[cur];
        #pragma unroll
        for (int s = 0; s < 4; ++s) {
            const int rowL = (ih * 4 + s) * 16 + l15;
            bf16x8 a0 = *(const bf16x8*)(prc + rowL * 128 + ((lg * 16)      ^ ((rowL & 7) << 4)));
            bf16x8 a1 = *(const bf16x8*)(prc + rowL * 128 + ((64 + lg * 16) ^ ((rowL & 7) << 4)));
            f32x4 e = {0.f, 0.f, 0.f, 0.f};
            e = MFMA_BF16(a0, b0, e);
            e = MFMA_BF16(a1, b1, e);
            bf16x4 phv;
            #pragma unroll
            for (int r = 0; r < 4; ++r) {
                float pf = EXP2(e[r]);
                z += pf;
                phv[r] = (bf16)pf;
            }
            const s4 pB = __builtin_bit_cast(s4, phv);
            const int colB = ((ih * 4 + s) * 16 + lg * 4) * 2;
            #pragma unroll
            for (int cb = 0; cb < 4; ++cb) {
                const int rowV = cb * 16 + l15;
                bf16x4 vt = *(const bf16x4*)(pvc + rowV * 256 + (colB ^ ((rowV & 15) << 4)));
                accWT[cb] = MFMA16(__builtin_bit_cast(s4, vt), pB, accWT[cb]);
            }
        }
        // write-late staged regs -> other buffer
        if (t < 31) {
            char* dpr = (char*)prL[cur ^ 1];
            char* dpv = (char*)pvL[cur ^ 1];
            const int o = tid * 32, o1 = o + 16;
            *(i32x4*)(dpr + (o  ^ (((o  >> 7) & 7) << 4))) = s0;
            *(i32x4*)(dpr + (o1 ^ (((o1 >> 7) & 7) << 4))) = s1;
            *(i32x4*)(dpv + (o  ^ (((o  >> 8) & 15) << 4))) = s2;
            *(i32x4*)(dpv + (o1 ^ (((o1 >> 8) & 15) << 4))) = s3;
        }
        __syncthreads();
        cur ^= 1;
    }

    // ---- Z: sum over lg within wave, combine ih pairs ----
    z += __shfl_xor(z, 16);
    z += __shfl_xor(z, 32);
    if (lane < 16) zred[w][lane] = z;
    __syncthreads();
    const float zj = zred[jt][l15] + zred[jt + 4][l15];
    float zinv = __builtin_amdgcn_rcpf(zj);
    zinv = zinv * (2.0f - zj * zinv);

    // ---- g[c] = sum_j W^T[c,j]*zinv_j : reduce over l15, then waves ----
    #pragma unroll
    for (int cb = 0; cb < 4; ++cb) {
        #pragma unroll
        for (int r = 0; r < 4; ++r) {
            float v = accWT[cb][r] * zinv;
            v += __shfl_xor(v, 1);
            v += __shfl_xor(v, 2);
            v += __shfl_xor(v, 4);
            v += __shfl_xor(v, 8);
            if (l15 == 0) gred[w][cb * 16 + lg * 4 + r] = v;
        }
    }
    __syncthreads();
    if (tid < 64) {
        float s = 0.f;
        #pragma unroll
        for (int k = 0; k < 8; ++k) s += gred[k][tid];
        gapPart[((size_t)b * 64 + jt64) * 64 + tid] = s;
    }
}

// ---------------------------------------------------------------------------
// K3: gap assembly -> mlp1+BN+ReLU -> mlp2+BN -> sigmoid (f32 out).
// ---------------------------------------------------------------------------
__global__ __launch_bounds__(256) void k_gate(
    const float* __restrict__ gapPart, const float* __restrict__ rgbdPart,
    const float* __restrict__ mlp1_w,
    const float* __restrict__ bn2_g, const float* __restrict__ bn2_b,
    const float* __restrict__ bn2_m, const float* __restrict__ bn2_v,
    const float* __restrict__ mlp2_w,
    const float* __restrict__ bn3_g, const float* __restrict__ bn3_b,
    const float* __restrict__ bn3_m, const float* __restrict__ bn3_v,
    float* __restrict__ out)
{
    const int b = blockIdx.x, tid = threadIdx.x;
    const int c = tid & 63, g = tid >> 6;
    __shared__ float red[4][64];
    __shared__ float gv[64], h[24];

    float acc = 0.f;
    const float* rp = rgbdPart + ((size_t)b * 128 + g * 32) * 64 + c;
    #pragma unroll 4
    for (int t = 0; t < 32; ++t) acc += rp[t * 64];
    const float* gp = gapPart + ((size_t)b * 64 + g * 16) * 64 + c;
    #pragma unroll 4
    for (int t = 0; t < 16; ++t) acc += gp[t * 64];
    red[g][c] = acc;
    __syncthreads();
    if (tid < 64)
        gv[tid] = ((red[0][tid] + red[1][tid]) + (red[2][tid] + red[3][tid]))
                  * (1.f / 4096.f);
    __syncthreads();
    if (tid < 24) {
        float a = 0.f;
        #pragma unroll
        for (int cc = 0; cc < 64; ++cc) a += mlp1_w[tid * 64 + cc] * gv[cc];
        float sc = bn2_g[tid] * rsqrtf(bn2_v[tid] + 1e-5f);
        a = a * sc + bn2_b[tid] - bn2_m[tid] * sc;
        h[tid] = a > 0.f ? a : 0.f;
    }
    __syncthreads();
    if (tid < 64) {
        float u = 0.f;
        #pragma unroll
        for (int o = 0; o < 24; ++o) u += mlp2_w[tid * 24 + o] * h[o];
        float sc = bn3_g[tid] * rsqrtf(bn3_v[tid] + 1e-5f);
        u = u * sc + bn3_b[tid] - bn3_m[tid] * sc;
        out[b * 64 + tid] = 1.f / (1.f + __expf(-u));
    }
}

// ---------------------------------------------------------------------------
extern "C" void kernel_launch(void* const* d_in, const int* in_sizes, int n_in,
                              void* d_out, int out_size, void* d_ws, size_t ws_size,
                              hipStream_t stream)
{
    const float* rgb    = (const float*)d_in[0];
    const float* dep    = (const float*)d_in[1];
    const float* conv_w = (const float*)d_in[2];
    const float* bn1_g  = (const float*)d_in[3];
    const float* bn1_b  = (const float*)d_in[4];
    const float* bn1_m  = (const float*)d_in[5];
    const float* bn1_v  = (const float*)d_in[6];
    const float* rgb_w  = (const float*)d_in[7];
    const float* dep_w  = (const float*)d_in[8];
    const float* mlp1_w = (const float*)d_in[9];
    const float* bn2_g  = (const float*)d_in[10];
    const float* bn2_b  = (const float*)d_in[11];
    const float* bn2_m  = (const float*)d_in[12];
    const float* bn2_v  = (const float*)d_in[13];
    const float* mlp2_w = (const float*)d_in[14];
    const float* bn3_g  = (const float*)d_in[15];
    const float* bn3_b  = (const float*)d_in[16];
    const float* bn3_m  = (const float*)d_in[17];
    const float* bn3_v  = (const float*)d_in[18];

    char* ws = (char*)d_ws;
    bf16*  pr_e     = (bf16*)(ws);                                  // 2 MB
    bf16*  pdBuf    = (bf16*)(ws + (2u << 20));                     // 2 MB
    bf16*  pvtBuf   = (bf16*)(ws + (4u << 20));                     // 2 MB
    float* rgbdPart = (float*)(ws + (6u << 20));                    // 128 KB
    float* gapPart  = (float*)(ws + (6u << 20) + (128u << 10));     // 64 KB
    bf16*  wC       = (bf16*)(ws + (6u << 20) + (192u << 10));      // 32 KB
    bf16*  wR       = (bf16*)(ws + (6u << 20) + (224u << 10));      // 8 KB
    bf16*  wD       = (bf16*)(ws + (6u << 20) + (232u << 10));      // 8 KB

    k_prep<<<12, 256, 0, stream>>>(conv_w, rgb_w, dep_w, wC, wR, wD);
    k_front<<<512, 512, 0, stream>>>(rgb, dep, wC, wR, wD,
                                     bn1_g, bn1_b, bn1_m, bn1_v,
                                     pr_e, pdBuf, pvtBuf, rgbdPart);
    k_colS<<<256, 512, 0, stream>>>(pr_e, pdBuf, pvtBuf, gapPart);
    k_gate<<<4, 256, 0, stream>>>(gapPart, rgbdPart, mlp1_w,
                                  bn2_g, bn2_b, bn2_m, bn2_v, mlp2_w,
                                  bn3_g, bn3_b, bn3_m, bn3_v, (float*)d_out);
}

// Round 11
// 48.340 us; speedup vs baseline: 4.1642x; 1.3627x over previous
//
#include <hip/hip_runtime.h>
#include <hip/hip_bf16.h>

// ---------------------------------------------------------------------------
// R11: attention stats with FRAGMENT-ORDER GLOBAL layouts — no LDS, no
// barriers, no address divergence in the hot loop.
//   gap_att[c] = sum_j W[j,c]/Z[j],  W[j,c] = sum_i p_ij v[i,c],
//   Z[j] = sum_i p_ij,  p_ij = exp2(e2_ij),  v = pr+pd.
// R10 lesson: LDS-staged version was LDS-pipe-bound (5.2M bank-conflict
// cycles, 76KB LDS -> 1 blk/CU). Fix: k_front stores pr/pd/pv permuted into
// MFMA fragment order, so every k_col load is base+lane*8B — coalesced:
//   prF/pdF: f(i,c) = (i>>4)*1024 + (c>>3)*128 + (i&15)*8 + (c&7)
//   pvF:     g(c,i) = (i>>4)*1024 + (c>>4)*256 + ((i>>2)&3)*64 + (c&15)*4 + (i&3)
// Each k_col wave owns ALL 4 j-subtiles (no inter-wave re-reads) and an
// exclusive i-slice: block reads pr/pv exactly once (1MB, L2-resident).
// ---------------------------------------------------------------------------

typedef __bf16 bf16;
typedef __bf16 bf16x4 __attribute__((ext_vector_type(4)));
typedef __bf16 bf16x8 __attribute__((ext_vector_type(8)));
typedef float  f32x4  __attribute__((ext_vector_type(4)));
typedef float  float4v __attribute__((ext_vector_type(4)));
typedef short  s4     __attribute__((ext_vector_type(4)));

#define MFMA_BF16(a, b, c) __builtin_amdgcn_mfma_f32_16x16x32_bf16((a), (b), (c), 0, 0, 0)

#if defined(__has_builtin)
# if __has_builtin(__builtin_amdgcn_mfma_f32_16x16x16bf16_1k)
#  define MFMA16_BUILTIN(a, b, c) __builtin_amdgcn_mfma_f32_16x16x16bf16_1k((a), (b), (c), 0, 0, 0)
# elif __has_builtin(__builtin_amdgcn_mfma_f32_16x16x16_bf16)
#  define MFMA16_BUILTIN(a, b, c) __builtin_amdgcn_mfma_f32_16x16x16_bf16((a), (b), (c), 0, 0, 0)
# endif
#endif

__device__ __forceinline__ f32x4 MFMA16(s4 a, s4 b, f32x4 c) {
#ifdef MFMA16_BUILTIN
    return MFMA16_BUILTIN(a, b, c);
#else
    asm("v_mfma_f32_16x16x16_bf16 %0, %1, %2, %0" : "+v"(c) : "v"(a), "v"(b));
    return c;
#endif
}

#if defined(__has_builtin)
# if __has_builtin(__builtin_amdgcn_exp2f)
#  define EXP2(x) __builtin_amdgcn_exp2f(x)
# else
#  define EXP2(x) exp2f(x)
# endif
#else
# define EXP2(x) exp2f(x)
#endif

#define K_E 0.18033688f      // 0.125 * log2(e)

__device__ __forceinline__ int swz128(int row, int colByte) {
    return row * 128 + (colByte ^ ((row & 7) << 4));
}
__device__ __forceinline__ int swz512(int row, int colByte) {
    return row * 512 + (colByte ^ ((row & 15) << 4));
}

// ---------------------------------------------------------------------------
// K0: pack weights into fragment-ordered bf16.
// ---------------------------------------------------------------------------
__global__ __launch_bounds__(256) void k_prep(
    const float* __restrict__ conv_w, const float* __restrict__ rgb_w,
    const float* __restrict__ dep_w,
    bf16* __restrict__ wC, bf16* __restrict__ wR, bf16* __restrict__ wD)
{
    const int gid = blockIdx.x * 256 + threadIdx.x;
    bf16x8 v;
    if (gid < 2048) {
        const int t = gid >> 9, kk = (gid >> 6) & 7, lane = gid & 63;
        const float* src = conv_w + (size_t)(t * 16 + (lane & 15)) * 256
                                  + kk * 32 + (lane >> 4) * 8;
        #pragma unroll
        for (int j = 0; j < 8; ++j) v[j] = (bf16)src[j];
        *(bf16x8*)(wC + (size_t)gid * 8) = v;
    } else if (gid < 2560) {
        const int g = gid - 2048;
        const int t = g >> 7, kk = (g >> 6) & 1, lane = g & 63;
        const float* src = rgb_w + (size_t)(t * 16 + (lane & 15)) * 64
                                 + kk * 32 + (lane >> 4) * 8;
        #pragma unroll
        for (int j = 0; j < 8; ++j) v[j] = (bf16)src[j];
        *(bf16x8*)(wR + (size_t)g * 8) = v;
    } else {
        const int g = gid - 2560;
        const int t = g >> 7, kk = (g >> 6) & 1, lane = g & 63;
        const float* src = dep_w + (size_t)(t * 16 + (lane & 15)) * 64
                                 + kk * 32 + (lane >> 4) * 8;
        #pragma unroll
        for (int j = 0; j < 8; ++j) v[j] = (bf16)src[j];
        *(bf16x8*)(wD + (size_t)g * 8) = v;
    }
}

// ---------------------------------------------------------------------------
// K1: staged conv+BN+ReLU -> proj; stores prF/pdF/pvF in FRAGMENT ORDER.
// 512 blocks XCD-affine x 512 thr (8 waves = 4 ot x 2 ph). Coalesced float4
// dep/rgb staging via LDS (R7-validated) replaces the divergent dep gather.
// ---------------------------------------------------------------------------
__global__ __launch_bounds__(512, 2) void k_front(
    const float* __restrict__ rgb, const float* __restrict__ dep,
    const bf16* __restrict__ wC, const bf16* __restrict__ wR,
    const bf16* __restrict__ wD,
    const float* __restrict__ bn1_g, const float* __restrict__ bn1_b,
    const float* __restrict__ bn1_m, const float* __restrict__ bn1_v,
    bf16* __restrict__ prF, bf16* __restrict__ pdF, bf16* __restrict__ pvF,
    float* __restrict__ rgbdPart)
{
    const int bid = blockIdx.x;
    const int xcd = bid & 7;
    const int b    = xcd >> 1;
    const int tile = ((bid >> 3) << 1) | (xcd & 1);   // 0..127
    const int p0   = tile * 32;
    const int tid = threadIdx.x;
    const int w   = tid >> 6;
    const int lane = tid & 63;
    const int l15 = lane & 15;
    const int lg  = lane >> 4;
    const int ot4 = w & 3;
    const int ot  = ot4 * 16;
    const int ph  = w >> 2;

    __shared__ float s1[64], b1[64];
    __shared__ __align__(16) unsigned char ldsC[32 * 512]; // dep [p][c256] swz
    __shared__ __align__(16) unsigned char ldsR[32 * 128]; // rgb [p][c64] swz
    __shared__ __align__(16) unsigned char ldsD[32 * 128]; // depf
    __shared__ float red[8][64];

    const float* depb = dep + (size_t)b * 256 * 4096;
    const float* rgbb = rgb + (size_t)b * 64 * 4096;

    // ---- stage dep (32KB f32 -> 16KB bf16) + rgb, coalesced float4 ----
    {
        const int c0 = tid >> 3, seg = tid & 7;
        #pragma unroll
        for (int r = 0; r < 4; ++r) {
            const int c = r * 64 + c0;
            float4v v = *(const float4v*)(depb + (size_t)c * 4096 + p0 + seg * 4);
            #pragma unroll
            for (int k = 0; k < 4; ++k)
                *(bf16*)(ldsC + swz512(seg * 4 + k, c * 2)) = (bf16)v[k];
        }
        float4v v = *(const float4v*)(rgbb + (size_t)c0 * 4096 + p0 + seg * 4);
        #pragma unroll
        for (int k = 0; k < 4; ++k)
            *(bf16*)(ldsR + swz128(seg * 4 + k, c0 * 2)) = (bf16)v[k];
        if (tid < 64) {
            float sc = bn1_g[tid] * rsqrtf(bn1_v[tid] + 1e-5f);
            s1[tid] = sc;
            b1[tid] = bn1_b[tid] - bn1_m[tid] * sc;
        }
    }
    __syncthreads();

    // ---- conv MFMA K=256 (A = packed wC, B = ldsC) ----
    const int prow = ph * 16 + l15;
    bf16x8 aW[8];
    #pragma unroll
    for (int kk = 0; kk < 8; ++kk)
        aW[kk] = *(const bf16x8*)(wC + ((size_t)(ot4 * 8 + kk) * 64 + lane) * 8);
    f32x4 acc = {0.f, 0.f, 0.f, 0.f};
    #pragma unroll
    for (int kk = 0; kk < 8; ++kk) {
        bf16x8 bF = *(const bf16x8*)(ldsC + swz512(prow, (kk * 32 + lg * 8) * 2));
        acc = MFMA_BF16(aW[kk], bF, acc);
    }
    {
        const int o0 = ot + lg * 4;
        bf16x4 v4;
        #pragma unroll
        for (int r = 0; r < 4; ++r) {
            float x = acc[r] * s1[o0 + r] + b1[o0 + r];
            v4[r] = (bf16)(x > 0.f ? x : 0.f);
        }
        *(bf16x4*)(ldsD + swz128(prow, o0 * 2)) = v4;
    }
    __syncthreads();

    // ---- proj GEMMs (K=64) ----
    bf16x8 aR[2], aD[2];
    #pragma unroll
    for (int kk = 0; kk < 2; ++kk) {
        aR[kk] = *(const bf16x8*)(wR + ((size_t)(ot4 * 2 + kk) * 64 + lane) * 8);
        aD[kk] = *(const bf16x8*)(wD + ((size_t)(ot4 * 2 + kk) * 64 + lane) * 8);
    }
    f32x4 accR = {0.f, 0.f, 0.f, 0.f}, accD = {0.f, 0.f, 0.f, 0.f};
    #pragma unroll
    for (int kk = 0; kk < 2; ++kk) {
        const int cb = (kk * 32 + lg * 8) * 2;
        bf16x8 bR = *(const bf16x8*)(ldsR + swz128(prow, cb));
        bf16x8 bD = *(const bf16x8*)(ldsD + swz128(prow, cb));
        accR = MFMA_BF16(aR[kk], bR, accR);
        accD = MFMA_BF16(aD[kk], bD, accD);
    }
    // ---- fragment-order stores ----
    {
        const int o0 = ot + lg * 4;
        const size_t itile = (size_t)tile * 2 + ph;     // i>>4, batch-local
        const size_t fbase = (size_t)b * 262144 + itile * 1024;
        // prF/pdF: f = itile*1024 + (c>>3)*128 + l15*8 + (c&7)
        const size_t prOff = fbase + (size_t)(o0 >> 3) * 128 + l15 * 8 + (o0 & 7);
        bf16x4 vR, vD;
        #pragma unroll
        for (int r = 0; r < 4; ++r) {
            vR[r] = (bf16)(accR[r] * K_E);
            vD[r] = (bf16)accD[r];
        }
        *(bf16x4*)(prF + prOff) = vR;
        *(bf16x4*)(pdF + prOff) = vD;
        // pvF: g = itile*1024 + ot4*256 + (l15>>2)*64 + lg*16 + (l15&3) + r*4
        const size_t pvBase = fbase + ot4 * 256 + (l15 >> 2) * 64 + lg * 16 + (l15 & 3);
        #pragma unroll
        for (int r = 0; r < 4; ++r)
            pvF[pvBase + r * 4] = (bf16)(accR[r] + accD[r]);
    }

    // ---- rgbd per-tile sums ----
    {
        const int c = tid & 63, g8 = tid >> 6;
        float sum = 0.f;
        #pragma unroll
        for (int q = 0; q < 4; ++q) {
            const int pp = g8 * 4 + q;
            sum += (float)*(const bf16*)(ldsR + swz128(pp, c * 2))
                 + (float)*(const bf16*)(ldsD + swz128(pp, c * 2));
        }
        red[g8][c] = sum;
    }
    __syncthreads();
    if (tid < 64) {
        float s = 0.f;
        #pragma unroll
        for (int g = 0; g < 8; ++g) s += red[g][tid];
        rgbdPart[((size_t)b * 128 + tile) * 64 + tid] = s;
    }
}

// ---------------------------------------------------------------------------
// K2: LDS-free single-pass column stats. 256 blocks (4b x 64 j-chunks of 64,
// XCD-affine) x 512 thr. Wave ih owns i-slice [ih*512, ih*512+512) and ALL
// 4 j-subtiles (b-frags resident; acc 16 f32x4). Per 16-i tile: 2 coalesced
// a-frag loads + 4 coalesced vt-frag loads -> 4x{2 eMFMA, 4 exp2, 4 MFMA16}.
// Epilogue only uses ~4.5KB LDS for cross-wave Z and gap reduction.
// ---------------------------------------------------------------------------
__global__ __launch_bounds__(512, 2) void k_col(
    const bf16* __restrict__ prF, const bf16* __restrict__ pdF,
    const bf16* __restrict__ pvF, float* __restrict__ gapPart)
{
    const int bid = blockIdx.x;
    const int xcd = bid & 7, b = xcd >> 1;
    const int jt64 = ((bid >> 3) << 1) | (xcd & 1);   // 0..63
    const int tid = threadIdx.x;
    const int ih = tid >> 6, lane = tid & 63;
    const int l15 = lane & 15, lg = lane >> 4;

    __shared__ float zred[8][64];
    __shared__ float zfull[64];
    __shared__ float gred[8][64];

    const bf16* prb = prF + (size_t)b * 262144;
    const bf16* pdb = pdF + (size_t)b * 262144;
    const bf16* pvb = pvF + (size_t)b * 262144;

    // resident b-frags for 4 j-subtiles (j = jt64*64 + jt*16 + l15)
    bf16x8 B0[4], B1[4];
    #pragma unroll
    for (int jt = 0; jt < 4; ++jt) {
        const bf16* q = pdb + (size_t)(jt64 * 4 + jt) * 1024 + lane * 8;
        B0[jt] = *(const bf16x8*)q;
        B1[jt] = *(const bf16x8*)(q + 512);
    }

    f32x4 acc[4][4];   // [jt][cb]
    #pragma unroll
    for (int jt = 0; jt < 4; ++jt)
        #pragma unroll
        for (int cb = 0; cb < 4; ++cb)
            acc[jt][cb] = (f32x4){0.f, 0.f, 0.f, 0.f};
    float z[4] = {0.f, 0.f, 0.f, 0.f};

    const bf16* pA = prb + (size_t)ih * 32 * 1024;    // 32 i-tiles per wave
    const bf16* pV = pvb + (size_t)ih * 32 * 1024;

    bf16x8 a0 = *(const bf16x8*)(pA + lane * 8);
    bf16x8 a1 = *(const bf16x8*)(pA + 512 + lane * 8);
    bf16x4 v0 = *(const bf16x4*)(pV + lane * 4);
    bf16x4 v1 = *(const bf16x4*)(pV + 256 + lane * 4);
    bf16x4 v2 = *(const bf16x4*)(pV + 512 + lane * 4);
    bf16x4 v3 = *(const bf16x4*)(pV + 768 + lane * 4);

    for (int t = 0; t < 32; ++t) {
        const bf16x8 ca0 = a0, ca1 = a1;
        const bf16x4 cv0 = v0, cv1 = v1, cv2 = v2, cv3 = v3;
        if (t < 31) {
            pA += 1024; pV += 1024;
            a0 = *(const bf16x8*)(pA + lane * 8);
            a1 = *(const bf16x8*)(pA + 512 + lane * 8);
            v0 = *(const bf16x4*)(pV + lane * 4);
            v1 = *(const bf16x4*)(pV + 256 + lane * 4);
            v2 = *(const bf16x4*)(pV + 512 + lane * 4);
            v3 = *(const bf16x4*)(pV + 768 + lane * 4);
        }
        #pragma unroll
        for (int jt = 0; jt < 4; ++jt) {
            f32x4 e = {0.f, 0.f, 0.f, 0.f};
            e = MFMA_BF16(ca0, B0[jt], e);
            e = MFMA_BF16(ca1, B1[jt], e);
            bf16x4 ph;
            #pragma unroll
            for (int r = 0; r < 4; ++r) {
                float pf = EXP2(e[r]);
                z[jt] += pf;
                ph[r] = (bf16)pf;
            }
            const s4 pB = __builtin_bit_cast(s4, ph);
            acc[jt][0] = MFMA16(__builtin_bit_cast(s4, cv0), pB, acc[jt][0]);
            acc[jt][1] = MFMA16(__builtin_bit_cast(s4, cv1), pB, acc[jt][1]);
            acc[jt][2] = MFMA16(__builtin_bit_cast(s4, cv2), pB, acc[jt][2]);
            acc[jt][3] = MFMA16(__builtin_bit_cast(s4, cv3), pB, acc[jt][3]);
        }
    }

    // ---- Z: reduce over lg (shfl) then over waves (LDS) ----
    #pragma unroll
    for (int jt = 0; jt < 4; ++jt) {
        float zv = z[jt];
        zv += __shfl_xor(zv, 16);
        zv += __shfl_xor(zv, 32);
        if (lane < 16) zred[ih][jt * 16 + lane] = zv;
    }
    __syncthreads();
    if (tid < 64) {
        float s = 0.f;
        #pragma unroll
        for (int k = 0; k < 8; ++k) s += zred[k][tid];
        zfull[tid] = s;
    }
    __syncthreads();

    // ---- g[c] = sum_jt sum_l15 acc*zinv; lane reduces jt in-reg ----
    float zinv[4];
    #pragma unroll
    for (int jt = 0; jt < 4; ++jt) {
        const float zj = zfull[jt * 16 + l15];
        float zi = __builtin_amdgcn_rcpf(zj);
        zinv[jt] = zi * (2.0f - zj * zi);
    }
    #pragma unroll
    for (int cb = 0; cb < 4; ++cb) {
        #pragma unroll
        for (int r = 0; r < 4; ++r) {
            float v = acc[0][cb][r] * zinv[0] + acc[1][cb][r] * zinv[1]
                    + acc[2][cb][r] * zinv[2] + acc[3][cb][r] * zinv[3];
            v += __shfl_xor(v, 1);
            v += __shfl_xor(v, 2);
            v += __shfl_xor(v, 4);
            v += __shfl_xor(v, 8);
            if (l15 == 0) gred[ih][cb * 16 + lg * 4 + r] = v;
        }
    }
    __syncthreads();
    if (tid < 64) {
        float s = 0.f;
        #pragma unroll
        for (int k = 0; k < 8; ++k) s += gred[k][tid];
        gapPart[((size_t)b * 64 + jt64) * 64 + tid] = s;
    }
}

// ---------------------------------------------------------------------------
// K3: gap assembly -> mlp1+BN+ReLU -> mlp2+BN -> sigmoid (f32 out).
// ---------------------------------------------------------------------------
__global__ __launch_bounds__(256) void k_gate(
    const float* __restrict__ gapPart, const float* __restrict__ rgbdPart,
    const float* __restrict__ mlp1_w,
    const float* __restrict__ bn2_g, const float* __restrict__ bn2_b,
    const float* __restrict__ bn2_m, const float* __restrict__ bn2_v,
    const float* __restrict__ mlp2_w,
    const float* __restrict__ bn3_g, const float* __restrict__ bn3_b,
    const float* __restrict__ bn3_m, const float* __restrict__ bn3_v,
    float* __restrict__ out)
{
    const int b = blockIdx.x, tid = threadIdx.x;
    const int c = tid & 63, g = tid >> 6;
    __shared__ float red[4][64];
    __shared__ float gv[64], h[24];

    float acc = 0.f;
    const float* rp = rgbdPart + ((size_t)b * 128 + g * 32) * 64 + c;
    #pragma unroll 4
    for (int t = 0; t < 32; ++t) acc += rp[t * 64];
    const float* gp = gapPart + ((size_t)b * 64 + g * 16) * 64 + c;
    #pragma unroll 4
    for (int t = 0; t < 16; ++t) acc += gp[t * 64];
    red[g][c] = acc;
    __syncthreads();
    if (tid < 64)
        gv[tid] = ((red[0][tid] + red[1][tid]) + (red[2][tid] + red[3][tid]))
                  * (1.f / 4096.f);
    __syncthreads();
    if (tid < 24) {
        float a = 0.f;
        #pragma unroll
        for (int cc = 0; cc < 64; ++cc) a += mlp1_w[tid * 64 + cc] * gv[cc];
        float sc = bn2_g[tid] * rsqrtf(bn2_v[tid] + 1e-5f);
        a = a * sc + bn2_b[tid] - bn2_m[tid] * sc;
        h[tid] = a > 0.f ? a : 0.f;
    }
    __syncthreads();
    if (tid < 64) {
        float u = 0.f;
        #pragma unroll
        for (int o = 0; o < 24; ++o) u += mlp2_w[tid * 24 + o] * h[o];
        float sc = bn3_g[tid] * rsqrtf(bn3_v[tid] + 1e-5f);
        u = u * sc + bn3_b[tid] - bn3_m[tid] * sc;
        out[b * 64 + tid] = 1.f / (1.f + __expf(-u));
    }
}

// ---------------------------------------------------------------------------
extern "C" void kernel_launch(void* const* d_in, const int* in_sizes, int n_in,
                              void* d_out, int out_size, void* d_ws, size_t ws_size,
                              hipStream_t stream)
{
    const float* rgb    = (const float*)d_in[0];
    const float* dep    = (const float*)d_in[1];
    const float* conv_w = (const float*)d_in[2];
    const float* bn1_g  = (const float*)d_in[3];
    const float* bn1_b  = (const float*)d_in[4];
    const float* bn1_m  = (const float*)d_in[5];
    const float* bn1_v  = (const float*)d_in[6];
    const float* rgb_w  = (const float*)d_in[7];
    const float* dep_w  = (const float*)d_in[8];
    const float* mlp1_w = (const float*)d_in[9];
    const float* bn2_g  = (const float*)d_in[10];
    const float* bn2_b  = (const float*)d_in[11];
    const float* bn2_m  = (const float*)d_in[12];
    const float* bn2_v  = (const float*)d_in[13];
    const float* mlp2_w = (const float*)d_in[14];
    const float* bn3_g  = (const float*)d_in[15];
    const float* bn3_b  = (const float*)d_in[16];
    const float* bn3_m  = (const float*)d_in[17];
    const float* bn3_v  = (const float*)d_in[18];

    char* ws = (char*)d_ws;
    bf16*  prF      = (bf16*)(ws);                                  // 2 MB
    bf16*  pdF      = (bf16*)(ws + (2u << 20));                     // 2 MB
    bf16*  pvF      = (bf16*)(ws + (4u << 20));                     // 2 MB
    float* rgbdPart = (float*)(ws + (6u << 20));                    // 128 KB
    float* gapPart  = (float*)(ws + (6u << 20) + (128u << 10));     // 64 KB
    bf16*  wC       = (bf16*)(ws + (6u << 20) + (192u << 10));      // 32 KB
    bf16*  wR       = (bf16*)(ws + (6u << 20) + (224u << 10));      // 8 KB
    bf16*  wD       = (bf16*)(ws + (6u << 20) + (232u << 10));      // 8 KB

    k_prep<<<12, 256, 0, stream>>>(conv_w, rgb_w, dep_w, wC, wR, wD);
    k_front<<<512, 512, 0, stream>>>(rgb, dep, wC, wR, wD,
                                     bn1_g, bn1_b, bn1_m, bn1_v,
                                     prF, pdF, pvF, rgbdPart);
    k_col<<<256, 512, 0, stream>>>(prF, pdF, pvF, gapPart);
    k_gate<<<4, 256, 0, stream>>>(gapPart, rgbdPart, mlp1_w,
                                  bn2_g, bn2_b, bn2_m, bn2_v, mlp2_w,
                                  bn3_g, bn3_b, bn3_m, bn3_v, (float*)d_out);
}